// Round 2
// baseline (170.332 us; speedup 1.0000x reference)
//
#include <hip/hip_runtime.h>
#include <hip/hip_bf16.h>

// ---------------------------------------------------------------------------
// Kernel 1: fused projection GEMM  Y = X * W^T + b  for q,k,v (blockIdx.z)
//   X: (1536, 256) row-major, W: (256, 256) row-major (d, k)
//   out permuted: out[((a*8+h)*384 + n)*32 + c], d = h*32+c
// grid (24, 4, 3), block 256. 64x64 tile, K-chunks of 16.
// ---------------------------------------------------------------------------
__global__ __launch_bounds__(256) void proj_kernel(
    const float* __restrict__ Xq, const float* __restrict__ Xk,
    const float* __restrict__ Xv,
    const float* __restrict__ Wq, const float* __restrict__ bq,
    const float* __restrict__ Wk, const float* __restrict__ bk,
    const float* __restrict__ Wv, const float* __restrict__ bv,
    float* __restrict__ oq, float* __restrict__ ok, float* __restrict__ ov)
{
    const int z = blockIdx.z;
    const float* X    = (z == 0) ? Xq : (z == 1) ? Xk : Xv;
    const float* W    = (z == 0) ? Wq : (z == 1) ? Wk : Wv;
    const float* bias = (z == 0) ? bq : (z == 1) ? bk : bv;
    float* out        = (z == 0) ? oq : (z == 1) ? ok : ov;

    __shared__ float Xs[64][17];
    __shared__ float Ws[64][17];
    const int tid = threadIdx.x;
    const int row0 = blockIdx.x * 64;
    const int col0 = blockIdx.y * 64;
    const int tx = tid & 15;
    const int ty = tid >> 4;

    float acc[4][4];
    #pragma unroll
    for (int i = 0; i < 4; ++i)
        #pragma unroll
        for (int j = 0; j < 4; ++j) acc[i][j] = 0.f;

    for (int kt = 0; kt < 256; kt += 16) {
        const int r  = tid >> 2;
        const int k4 = (tid & 3) * 4;
        float4 xv = *(const float4*)&X[(row0 + r) * 256 + kt + k4];
        Xs[r][k4 + 0] = xv.x; Xs[r][k4 + 1] = xv.y;
        Xs[r][k4 + 2] = xv.z; Xs[r][k4 + 3] = xv.w;
        float4 wv = *(const float4*)&W[(col0 + r) * 256 + kt + k4];
        Ws[r][k4 + 0] = wv.x; Ws[r][k4 + 1] = wv.y;
        Ws[r][k4 + 2] = wv.z; Ws[r][k4 + 3] = wv.w;
        __syncthreads();
        #pragma unroll
        for (int kk = 0; kk < 16; ++kk) {
            float xr[4], wc[4];
            #pragma unroll
            for (int i = 0; i < 4; ++i) xr[i] = Xs[ty + 16 * i][kk];
            #pragma unroll
            for (int j = 0; j < 4; ++j) wc[j] = Ws[tx + 16 * j][kk];
            #pragma unroll
            for (int i = 0; i < 4; ++i)
                #pragma unroll
                for (int j = 0; j < 4; ++j) acc[i][j] += xr[i] * wc[j];
        }
        __syncthreads();
    }

    #pragma unroll
    for (int i = 0; i < 4; ++i) {
        const int row = row0 + ty + 16 * i;
        const int a = row / 384;
        const int n = row - a * 384;
        #pragma unroll
        for (int j = 0; j < 4; ++j) {
            const int d = col0 + tx + 16 * j;
            const int h = d >> 5;
            const int c = d & 31;
            out[((a * 8 + h) * 384 + n) * 32 + c] = acc[i][j] + bias[d];
        }
    }
}

// ---------------------------------------------------------------------------
// Kernel 2: split-m flash attention partials + in-block merge.
// grid (6, 128): x = row-block (64 rows), y = (a*4+e)*8+h ... y = a*32+e*8+h
// block 256: tid&63 = row in tile, tid>>6 = m-chunk (96 keys each).
// K/V read directly from global (wave-broadcast, L2-resident; no staging).
// Writes normalized S(a,e)[h][n][c] and per-block raw-score-sum partial.
// ---------------------------------------------------------------------------
__global__ __launch_bounds__(256, 3) void attn_part_kernel(
    const float* __restrict__ qb, const float* __restrict__ kb,
    const float* __restrict__ vb, float* __restrict__ Sout,
    float* __restrict__ msum_part)
{
    __shared__ float acc_lds[4][64][33];
    __shared__ float ml[4][64];
    __shared__ float ll[4][64];
    __shared__ float red[256];

    const int rowblk = blockIdx.x;
    const int y = blockIdx.y;
    const int h = y & 7;
    const int e = (y >> 3) & 3;
    const int a = y >> 5;
    const int tid = threadIdx.x;
    const int lr = tid & 63;
    const int ch = tid >> 6;
    const int n = rowblk * 64 + lr;

    const float* qp = qb + (size_t)((a * 8 + h) * 384 + n) * 32;
    float qv[32];
    #pragma unroll
    for (int c4 = 0; c4 < 8; ++c4) {
        float4 q4 = ((const float4*)qp)[c4];
        qv[4 * c4 + 0] = q4.x; qv[4 * c4 + 1] = q4.y;
        qv[4 * c4 + 2] = q4.z; qv[4 * c4 + 3] = q4.w;
    }

    const float* kp = kb + (size_t)((e * 8 + h) * 384 + ch * 96) * 32;
    const float* vp = vb + (size_t)((e * 8 + h) * 384 + ch * 96) * 32;

    float acc[32];
    #pragma unroll
    for (int c = 0; c < 32; ++c) acc[c] = 0.f;
    float mx = -INFINITY, l = 0.f, rawsum = 0.f;
    const float sc = 0.17677669529663687f; // 1/sqrt(32)

    for (int m0 = 0; m0 < 96; m0 += 8) {
        float s[8];
        #pragma unroll
        for (int j = 0; j < 8; ++j) {
            const float4* kr = (const float4*)&kp[(m0 + j) * 32];
            float t0 = 0.f, t1 = 0.f, t2 = 0.f, t3 = 0.f;
            #pragma unroll
            for (int c4 = 0; c4 < 8; ++c4) {
                float4 kv = kr[c4];
                t0 += qv[4 * c4 + 0] * kv.x;
                t1 += qv[4 * c4 + 1] * kv.y;
                t2 += qv[4 * c4 + 2] * kv.z;
                t3 += qv[4 * c4 + 3] * kv.w;
            }
            s[j] = (t0 + t1 + t2 + t3) * sc;
        }
        float cm = s[0];
        #pragma unroll
        for (int j = 1; j < 8; ++j) cm = fmaxf(cm, s[j]);
        #pragma unroll
        for (int j = 0; j < 8; ++j) rawsum += s[j];

        const float nm = fmaxf(mx, cm);
        const float scale = __expf(mx - nm); // first iter: exp(-inf)=0
        mx = nm;
        l *= scale;
        #pragma unroll
        for (int c = 0; c < 32; ++c) acc[c] *= scale;

        float p[8];
        #pragma unroll
        for (int j = 0; j < 8; ++j) { p[j] = __expf(s[j] - nm); l += p[j]; }

        #pragma unroll
        for (int j = 0; j < 8; ++j) {
            const float pj = p[j];
            const float4* vr = (const float4*)&vp[(m0 + j) * 32];
            #pragma unroll
            for (int c4 = 0; c4 < 8; ++c4) {
                float4 vv = vr[c4];
                acc[4 * c4 + 0] += pj * vv.x;
                acc[4 * c4 + 1] += pj * vv.y;
                acc[4 * c4 + 2] += pj * vv.z;
                acc[4 * c4 + 3] += pj * vv.w;
            }
        }
    }

    // publish partials to LDS
    ml[ch][lr] = mx;
    ll[ch][lr] = l;
    #pragma unroll
    for (int c = 0; c < 32; ++c) acc_lds[ch][lr][c] = acc[c];
    red[tid] = rawsum;
    __syncthreads();

    // raw-score-sum block reduction (deterministic)
    #pragma unroll
    for (int off = 128; off >= 1; off >>= 1) {
        if (tid < off) red[tid] += red[tid + off];
        __syncthreads();
    }
    if (tid == 0) msum_part[y * 6 + rowblk] = red[0];

    // merge 4 m-chunk partials: thread = (row r_, channel-quad cq)
    const int r_ = lr;
    const int cq = ch;
    const float m0v = ml[0][r_], m1v = ml[1][r_], m2v = ml[2][r_], m3v = ml[3][r_];
    const float M = fmaxf(fmaxf(m0v, m1v), fmaxf(m2v, m3v));
    const float e0 = __expf(m0v - M), e1 = __expf(m1v - M);
    const float e2 = __expf(m2v - M), e3 = __expf(m3v - M);
    const float L = ll[0][r_] * e0 + ll[1][r_] * e1 + ll[2][r_] * e2 + ll[3][r_] * e3;
    const float inv = 1.f / L;

    float o[8];
    #pragma unroll
    for (int c = 0; c < 8; ++c) {
        const int cc = cq * 8 + c;
        float sgm = acc_lds[0][r_][cc] * e0 + acc_lds[1][r_][cc] * e1
                  + acc_lds[2][r_][cc] * e2 + acc_lds[3][r_][cc] * e3;
        o[c] = sgm * inv;
    }
    float* so = Sout + (size_t)(((a * 4 + e) * 8 + h) * 384 + rowblk * 64 + r_) * 32 + cq * 8;
    ((float4*)so)[0] = make_float4(o[0], o[1], o[2], o[3]);
    ((float4*)so)[1] = make_float4(o[4], o[5], o[6], o[7]);
}

// ---------------------------------------------------------------------------
// Kernel 3: reduce 768 partials -> 16 cell sums -> pooled[12] -> weights[16]
// ---------------------------------------------------------------------------
__global__ __launch_bounds__(256) void stats_kernel(
    const float* __restrict__ msum_part, float* __restrict__ wout)
{
    __shared__ float sh[128];
    __shared__ float cell[16];
    const int tid = threadIdx.x;
    if (tid < 128) {
        float s = 0.f;
        #pragma unroll
        for (int j = 0; j < 6; ++j) s += msum_part[tid * 6 + j];
        sh[tid] = s;
    }
    __syncthreads();
    if (tid < 16) {
        const int base = (tid >> 2) * 32 + (tid & 3) * 8; // a*32 + e*8
        float s = 0.f;
        #pragma unroll
        for (int hh = 0; hh < 8; ++hh) s += sh[base + hh];
        cell[tid] = s;
    }
    __syncthreads();
    if (tid == 0) {
        const int TR[12][4] = {
            {0,1,2,3},{0,2,3,1},{0,3,1,2},{1,2,0,3},{1,0,3,2},{1,3,2,0},
            {2,3,0,1},{2,0,1,3},{2,1,3,0},{3,1,0,2},{3,0,2,1},{3,2,1,0}};
        const float denom = 4.0f * 8.0f * 384.0f * 384.0f;
        float pos[12];
        float psum = 0.f;
        for (int r = 0; r < 12; ++r) {
            float s = 0.f;
            for (int aa = 0; aa < 4; ++aa) s += cell[aa * 4 + TR[r][aa]];
            const float pooled = s / denom;
            pos[r] = pooled * pooled;
            psum += pos[r];
        }
        float w[16];
        for (int i = 0; i < 16; ++i) w[i] = 0.f;
        const float ip = 1.f / psum;
        for (int r = 0; r < 12; ++r)
            for (int aa = 0; aa < 4; ++aa) w[aa * 4 + TR[r][aa]] += pos[r] * ip;
        for (int i = 0; i < 16; ++i) wout[i] = w[i];
    }
}

// ---------------------------------------------------------------------------
// Kernel 4: out[a,n,h*32+c] = sum_e w[a,e] * S[(a,e),h,n,c]
// ---------------------------------------------------------------------------
__global__ __launch_bounds__(256) void combine_kernel(
    const float* __restrict__ S, const float* __restrict__ w,
    float* __restrict__ out)
{
    const int idx = blockIdx.x * 256 + threadIdx.x;
    const int a = idx / 98304;
    const int rem = idx - a * 98304;
    const int n = rem >> 8;
    const int d = rem & 255;
    const int h = d >> 5;
    const int c = d & 31;
    float r = 0.f;
    #pragma unroll
    for (int e = 0; e < 4; ++e)
        r += w[a * 4 + e] * S[(size_t)(((a * 4 + e) * 8 + h) * 384 + n) * 32 + c];
    out[idx] = r;
}

// ---------------------------------------------------------------------------
extern "C" void kernel_launch(void* const* d_in, const int* in_sizes, int n_in,
                              void* d_out, int out_size, void* d_ws, size_t ws_size,
                              hipStream_t stream)
{
    const float* in_q = (const float*)d_in[0];
    const float* in_k = (const float*)d_in[1];
    const float* in_v = (const float*)d_in[2];
    const float* Wq   = (const float*)d_in[3];
    const float* bq   = (const float*)d_in[4];
    const float* Wk   = (const float*)d_in[5];
    const float* bk   = (const float*)d_in[6];
    const float* Wv   = (const float*)d_in[7];
    const float* bv   = (const float*)d_in[8];

    float* ws  = (float*)d_ws;
    float* qb  = ws;                  // 393216
    float* kb  = qb + 393216;         // 393216
    float* vb  = kb + 393216;         // 393216
    float* Sb  = vb + 393216;         // 1572864
    float* ms  = Sb + 1572864;        // 768
    float* wb  = ms + 768;            // 16
    float* outp = (float*)d_out;

    dim3 pgrid(24, 4, 3);
    proj_kernel<<<pgrid, 256, 0, stream>>>(in_q, in_k, in_v, Wq, bq, Wk, bk,
                                           Wv, bv, qb, kb, vb);
    dim3 agrid(6, 128);
    attn_part_kernel<<<agrid, 256, 0, stream>>>(qb, kb, vb, Sb, ms);
    stats_kernel<<<1, 256, 0, stream>>>(ms, wb);
    combine_kernel<<<1536, 256, 0, stream>>>(Sb, wb, outp);
}

// Round 3
// 53.967 us; speedup vs baseline: 3.1563x; 3.1563x over previous
//
#include <hip/hip_runtime.h>
#include <hip/hip_bf16.h>

typedef __attribute__((ext_vector_type(8))) short s8x8;
typedef __attribute__((ext_vector_type(4))) float f32x4;

__device__ __forceinline__ ushort f2bf(float x) {
    union { float f; unsigned u; } c; c.f = x;
    unsigned r = c.u + 0x7FFFu + ((c.u >> 16) & 1u);
    return (ushort)(r >> 16);
}
__device__ __forceinline__ float bf2f(ushort b) {
    union { unsigned u; float f; } c; c.u = ((unsigned)b) << 16;
    return c.f;
}

// ---------------------------------------------------------------------------
// Kernel 1: fused projection GEMM  Y = X*W^T + b  for q,k,v (blockIdx.z).
// Outputs bf16 hi/lo buffers in MFMA-operand-friendly layouts:
//   z=0 (q): q_hi/q_lo  [(a*8+h)][n][c]         (row-major, A-frag direct)
//   z=1 (k): k_hi/k_lo  [(e*8+h)][kblk=c/8][m][c%8]  (B-frag 16B units)
//   z=2 (v): v_hi       [(e*8+h)*32 + c][m]     (transposed via LDS)
// ---------------------------------------------------------------------------
__global__ __launch_bounds__(256) void proj_kernel(
    const float* __restrict__ Xq, const float* __restrict__ Xk,
    const float* __restrict__ Xv,
    const float* __restrict__ Wq, const float* __restrict__ bq,
    const float* __restrict__ Wk, const float* __restrict__ bk,
    const float* __restrict__ Wv, const float* __restrict__ bv,
    ushort* __restrict__ qh, ushort* __restrict__ ql,
    ushort* __restrict__ kh, ushort* __restrict__ kl,
    ushort* __restrict__ vh)
{
    const int z = blockIdx.z;
    const float* X    = (z == 0) ? Xq : (z == 1) ? Xk : Xv;
    const float* W    = (z == 0) ? Wq : (z == 1) ? Wk : Wv;
    const float* bias = (z == 0) ? bq : (z == 1) ? bk : bv;

    __shared__ float Xs[64][17];
    __shared__ float Ws[64][17];
    __shared__ float T[64][65];

    const int tid = threadIdx.x;
    const int row0 = blockIdx.x * 64;
    const int col0 = blockIdx.y * 64;
    const int tx = tid & 15;
    const int ty = tid >> 4;

    float acc[4][4];
    #pragma unroll
    for (int i = 0; i < 4; ++i)
        #pragma unroll
        for (int j = 0; j < 4; ++j) acc[i][j] = 0.f;

    for (int kt = 0; kt < 256; kt += 16) {
        const int r  = tid >> 2;
        const int k4 = (tid & 3) * 4;
        float4 xv = *(const float4*)&X[(row0 + r) * 256 + kt + k4];
        Xs[r][k4 + 0] = xv.x; Xs[r][k4 + 1] = xv.y;
        Xs[r][k4 + 2] = xv.z; Xs[r][k4 + 3] = xv.w;
        float4 wv = *(const float4*)&W[(col0 + r) * 256 + kt + k4];
        Ws[r][k4 + 0] = wv.x; Ws[r][k4 + 1] = wv.y;
        Ws[r][k4 + 2] = wv.z; Ws[r][k4 + 3] = wv.w;
        __syncthreads();
        #pragma unroll
        for (int kk = 0; kk < 16; ++kk) {
            float xr[4], wc[4];
            #pragma unroll
            for (int i = 0; i < 4; ++i) xr[i] = Xs[ty + 16 * i][kk];
            #pragma unroll
            for (int j = 0; j < 4; ++j) wc[j] = Ws[tx + 16 * j][kk];
            #pragma unroll
            for (int i = 0; i < 4; ++i)
                #pragma unroll
                for (int j = 0; j < 4; ++j) acc[i][j] += xr[i] * wc[j];
        }
        __syncthreads();
    }

    if (z != 2) {
        #pragma unroll
        for (int i = 0; i < 4; ++i) {
            const int row = row0 + ty + 16 * i;
            const int ae = row / 384;      // a for q, e for k
            const int n = row - ae * 384;
            #pragma unroll
            for (int j = 0; j < 4; ++j) {
                const int d = col0 + tx + 16 * j;
                const int hd = d >> 5;
                const int c = d & 31;
                const float v = acc[i][j] + bias[d];
                const ushort hb = f2bf(v);
                const ushort lb = f2bf(v - bf2f(hb));
                if (z == 0) {
                    const size_t idx = ((size_t)((ae * 8 + hd) * 384 + n)) * 32 + c;
                    qh[idx] = hb; ql[idx] = lb;
                } else {
                    const size_t idx =
                        ((size_t)(((ae * 8 + hd) * 4 + (c >> 3)) * 384 + n)) * 8 + (c & 7);
                    kh[idx] = hb; kl[idx] = lb;
                }
            }
        }
    } else {
        // v: stage fp32 into LDS, re-read transposed, coalesced bf16 stores
        #pragma unroll
        for (int i = 0; i < 4; ++i)
            #pragma unroll
            for (int j = 0; j < 4; ++j)
                T[ty + 16 * i][tx + 16 * j] = acc[i][j] + bias[col0 + tx + 16 * j];
        __syncthreads();
        const int cc_l = tid >> 2;          // 0..63 local c
        const int nb = (tid & 3) * 16;      // n sub-chunk
        const int d = col0 + cc_l;
        const int hd = d >> 5;
        const int c = d & 31;
        const int ae = row0 / 384;          // e (blocks never straddle)
        const int e8h = ae * 8 + hd;
        ushort hbuf[16] __attribute__((aligned(16)));
        #pragma unroll
        for (int k16 = 0; k16 < 16; ++k16)
            hbuf[k16] = f2bf(T[nb + k16][cc_l]);
        const size_t base = (size_t)(e8h * 32 + c) * 384 + (row0 % 384) + nb;
        *(uint4*)&vh[base] = *(const uint4*)&hbuf[0];
        *(uint4*)&vh[base + 8] = *(const uint4*)&hbuf[8];
    }
}

// ---------------------------------------------------------------------------
// Kernel 2: MFMA flash attention per (a,e,h) x n-strip(96).
// grid (4, 128), block 192 (3 waves, 2 row-tiles of 16 each).
// m processed in two staged halves of 192. No online max (|s·sc| <= ~6).
// 3-term hi/lo QK^T, 2-term hi/lo PV. Writes normalized S + rawsum partial.
// ---------------------------------------------------------------------------
__global__ __launch_bounds__(192) void attn_mfma_kernel(
    const ushort* __restrict__ qhb, const ushort* __restrict__ qlb,
    const ushort* __restrict__ khb, const ushort* __restrict__ klb,
    const ushort* __restrict__ vhb,
    float* __restrict__ Sout, float* __restrict__ msum_part)
{
    __shared__ ushort Kh[4 * 192 * 8];
    __shared__ ushort Kl[4 * 192 * 8];
    __shared__ ushort Vh[32 * 200];
    __shared__ float  Pl[3][2][16][36];
    __shared__ float  red[192];

    const int strip = blockIdx.x;
    const int aeh   = blockIdx.y;          // a*32 + e*8 + h
    const int hh    = aeh & 7;
    const int ee    = (aeh >> 3) & 3;
    const int aa    = aeh >> 5;
    const int e8h   = ee * 8 + hh;
    const int a8h   = aa * 8 + hh;
    const int tid   = threadIdx.x;
    const int wave  = tid >> 6;
    const int lane  = tid & 63;
    const int lg    = lane >> 4;
    const int ll    = lane & 15;

    // Q A-fragments (hi/lo) for this wave's two row-tiles, straight from global
    s8x8 qfh[2], qfl[2];
    #pragma unroll
    for (int r = 0; r < 2; ++r) {
        const int n0 = strip * 96 + (2 * wave + r) * 16;
        const size_t off = (size_t)(a8h * 384 + n0 + ll) * 32 + lg * 8;
        qfh[r] = *(const s8x8*)&qhb[off];
        qfl[r] = *(const s8x8*)&qlb[off];
    }

    f32x4 oacc[2][2];
    #pragma unroll
    for (int r = 0; r < 2; ++r)
        #pragma unroll
        for (int ct = 0; ct < 2; ++ct)
            oacc[r][ct] = (f32x4){0.f, 0.f, 0.f, 0.f};
    float lsum[2][4];
    #pragma unroll
    for (int r = 0; r < 2; ++r)
        #pragma unroll
        for (int j = 0; j < 4; ++j) lsum[r][j] = 0.f;
    float rs = 0.f;
    const float sc = 0.17677669529663687f; // 1/sqrt(32)

    for (int half = 0; half < 2; ++half) {
        // stage K hi/lo ([kblk][192][8]) and V^T ([32][200]) for this m-half
        #pragma unroll
        for (int i = 0; i < 4; ++i) {
            const size_t src = ((size_t)(e8h * 4 + i) * 384 + half * 192 + tid) * 8;
            *(uint4*)&Kh[(i * 192 + tid) * 8] = *(const uint4*)&khb[src];
            *(uint4*)&Kl[(i * 192 + tid) * 8] = *(const uint4*)&klb[src];
        }
        #pragma unroll
        for (int i = 0; i < 4; ++i) {
            const int u = tid + 192 * i;
            const int c = u / 24;
            const int m8 = (u - c * 24) * 8;
            *(uint4*)&Vh[c * 200 + m8] =
                *(const uint4*)&vhb[(size_t)(e8h * 32 + c) * 384 + half * 192 + m8];
        }
        __syncthreads();

        for (int mt2 = 0; mt2 < 6; ++mt2) {
            #pragma unroll
            for (int sub = 0; sub < 2; ++sub) {
                const int mt = mt2 * 2 + sub;
                const s8x8 kfh = *(const s8x8*)&Kh[(lg * 192 + mt * 16 + ll) * 8];
                const s8x8 kfl = *(const s8x8*)&Kl[(lg * 192 + mt * 16 + ll) * 8];
                #pragma unroll
                for (int r = 0; r < 2; ++r) {
                    f32x4 s = {0.f, 0.f, 0.f, 0.f};
                    s = __builtin_amdgcn_mfma_f32_16x16x32_bf16(qfh[r], kfh, s, 0, 0, 0);
                    s = __builtin_amdgcn_mfma_f32_16x16x32_bf16(qfl[r], kfh, s, 0, 0, 0);
                    s = __builtin_amdgcn_mfma_f32_16x16x32_bf16(qfh[r], kfl, s, 0, 0, 0);
                    rs += s[0] + s[1] + s[2] + s[3];
                    #pragma unroll
                    for (int j = 0; j < 4; ++j) {
                        const float p = __expf(s[j] * sc);
                        lsum[r][j] += p;
                        Pl[wave][r][lg * 4 + j][sub * 16 + ll] = p;
                    }
                }
            }
            // PV over the 32 freshly produced columns
            const int mloc = mt2 * 32;
            const s8x8 vf0 = *(const s8x8*)&Vh[(0  + ll) * 200 + mloc + lg * 8];
            const s8x8 vf1 = *(const s8x8*)&Vh[(16 + ll) * 200 + mloc + lg * 8];
            #pragma unroll
            for (int r = 0; r < 2; ++r) {
                const float* prow = &Pl[wave][r][ll][lg * 8];
                s8x8 pah, pal;
                #pragma unroll
                for (int e2 = 0; e2 < 8; ++e2) {
                    const float pv = prow[e2];
                    const ushort hb = f2bf(pv);
                    pah[e2] = (short)hb;
                    pal[e2] = (short)f2bf(pv - bf2f(hb));
                }
                oacc[r][0] = __builtin_amdgcn_mfma_f32_16x16x32_bf16(pah, vf0, oacc[r][0], 0, 0, 0);
                oacc[r][0] = __builtin_amdgcn_mfma_f32_16x16x32_bf16(pal, vf0, oacc[r][0], 0, 0, 0);
                oacc[r][1] = __builtin_amdgcn_mfma_f32_16x16x32_bf16(pah, vf1, oacc[r][1], 0, 0, 0);
                oacc[r][1] = __builtin_amdgcn_mfma_f32_16x16x32_bf16(pal, vf1, oacc[r][1], 0, 0, 0);
            }
        }
        __syncthreads();
    }

    // finalize: per-row L (reduce across the 16 col-lanes), normalize, write S
    #pragma unroll
    for (int r = 0; r < 2; ++r) {
        #pragma unroll
        for (int j = 0; j < 4; ++j) {
            float L = lsum[r][j];
            L += __shfl_xor(L, 1);
            L += __shfl_xor(L, 2);
            L += __shfl_xor(L, 4);
            L += __shfl_xor(L, 8);
            const float invL = 1.f / L;
            const int row = strip * 96 + (2 * wave + r) * 16 + lg * 4 + j;
            const size_t base = (size_t)(aeh * 384 + row) * 32;
            Sout[base + 0  + ll] = oacc[r][0][j] * invL;
            Sout[base + 16 + ll] = oacc[r][1][j] * invL;
        }
    }

    // rawsum partial (scale once by sc), deterministic block tree
    red[tid] = rs * sc;
    __syncthreads();
    for (int off = 96; off >= 3; off >>= 1) {
        if (tid < off) red[tid] += red[tid + off];
        __syncthreads();
    }
    if (tid == 0) msum_part[aeh * 4 + strip] = red[0] + red[1] + red[2];
}

// ---------------------------------------------------------------------------
// Kernel 3: 512 partials -> 16 cell sums -> pooled[12] -> weights[16]
// ---------------------------------------------------------------------------
__global__ __launch_bounds__(256) void stats_kernel(
    const float* __restrict__ msum_part, float* __restrict__ wout)
{
    __shared__ float sh[128];
    __shared__ float cell[16];
    const int tid = threadIdx.x;
    if (tid < 128) {
        float s = 0.f;
        #pragma unroll
        for (int j = 0; j < 4; ++j) s += msum_part[tid * 4 + j];
        sh[tid] = s;
    }
    __syncthreads();
    if (tid < 16) {
        const int base = (tid >> 2) * 32 + (tid & 3) * 8; // a*32 + e*8
        float s = 0.f;
        #pragma unroll
        for (int hh = 0; hh < 8; ++hh) s += sh[base + hh];
        cell[tid] = s;
    }
    __syncthreads();
    if (tid == 0) {
        const int TR[12][4] = {
            {0,1,2,3},{0,2,3,1},{0,3,1,2},{1,2,0,3},{1,0,3,2},{1,3,2,0},
            {2,3,0,1},{2,0,1,3},{2,1,3,0},{3,1,0,2},{3,0,2,1},{3,2,1,0}};
        const float denom = 4.0f * 8.0f * 384.0f * 384.0f;
        float pos[12];
        float psum = 0.f;
        for (int r = 0; r < 12; ++r) {
            float s = 0.f;
            for (int aa = 0; aa < 4; ++aa) s += cell[aa * 4 + TR[r][aa]];
            const float pooled = s / denom;
            pos[r] = pooled * pooled;
            psum += pos[r];
        }
        float w[16];
        for (int i = 0; i < 16; ++i) w[i] = 0.f;
        const float ip = 1.f / psum;
        for (int r = 0; r < 12; ++r)
            for (int aa = 0; aa < 4; ++aa) w[aa * 4 + TR[r][aa]] += pos[r] * ip;
        for (int i = 0; i < 16; ++i) wout[i] = w[i];
    }
}

// ---------------------------------------------------------------------------
// Kernel 4: out[a,n,h*32+c] = sum_e w[a,e] * S[(a,e),h,n,c]
// ---------------------------------------------------------------------------
__global__ __launch_bounds__(256) void combine_kernel(
    const float* __restrict__ S, const float* __restrict__ w,
    float* __restrict__ out)
{
    const int idx = blockIdx.x * 256 + threadIdx.x;
    const int a = idx / 98304;
    const int rem = idx - a * 98304;
    const int n = rem >> 8;
    const int d = rem & 255;
    const int h = d >> 5;
    const int c = d & 31;
    float r = 0.f;
    #pragma unroll
    for (int e = 0; e < 4; ++e)
        r += w[a * 4 + e] * S[(size_t)(((a * 4 + e) * 8 + h) * 384 + n) * 32 + c];
    out[idx] = r;
}

// ---------------------------------------------------------------------------
extern "C" void kernel_launch(void* const* d_in, const int* in_sizes, int n_in,
                              void* d_out, int out_size, void* d_ws, size_t ws_size,
                              hipStream_t stream)
{
    const float* in_q = (const float*)d_in[0];
    const float* in_k = (const float*)d_in[1];
    const float* in_v = (const float*)d_in[2];
    const float* Wq   = (const float*)d_in[3];
    const float* bq   = (const float*)d_in[4];
    const float* Wk   = (const float*)d_in[5];
    const float* bk   = (const float*)d_in[6];
    const float* Wv   = (const float*)d_in[7];
    const float* bv   = (const float*)d_in[8];

    const size_t NE = 393216; // elements per projected tensor
    ushort* qh = (ushort*)d_ws;
    ushort* ql = qh + NE;
    ushort* kh = ql + NE;
    ushort* kl = kh + NE;
    ushort* vh = kl + NE;
    float*  Sb = (float*)((char*)d_ws + 5 * NE * sizeof(ushort));
    float*  ms = Sb + 1572864;   // 512 partials
    float*  wb = ms + 512;       // 16 weights
    float*  outp = (float*)d_out;

    dim3 pgrid(24, 4, 3);
    proj_kernel<<<pgrid, 256, 0, stream>>>(in_q, in_k, in_v, Wq, bq, Wk, bk,
                                           Wv, bv, qh, ql, kh, kl, vh);
    dim3 agrid(4, 128);
    attn_mfma_kernel<<<agrid, 192, 0, stream>>>(qh, ql, kh, kl, vh, Sb, ms);
    stats_kernel<<<1, 256, 0, stream>>>(ms, wb);
    combine_kernel<<<1536, 256, 0, stream>>>(Sb, wb, outp);
}

// Round 4
// 43.387 us; speedup vs baseline: 3.9259x; 1.2438x over previous
//
#include <hip/hip_runtime.h>
#include <hip/hip_bf16.h>

typedef __attribute__((ext_vector_type(8))) short s8x8;
typedef __attribute__((ext_vector_type(4))) float f32x4;

__device__ __forceinline__ ushort f2bf(float x) {
    union { float f; unsigned u; } c; c.f = x;
    unsigned r = c.u + 0x7FFFu + ((c.u >> 16) & 1u);
    return (ushort)(r >> 16);
}
__device__ __forceinline__ float bf2f(ushort b) {
    union { unsigned u; float f; } c; c.u = ((unsigned)b) << 16;
    return c.f;
}

// ---------------------------------------------------------------------------
// Kernel 1: MFMA projection GEMM  Y = X*W^T + b  for q,k,v (blockIdx.z).
// Block 128 thr (2 waves), tile 64 rows x 64 cols, grid (24,4,3).
// W fp32 -> bf16 hi/lo staged in LDS in B-frag layout [kk][lg][col][8].
// X fp32 loaded per-lane from global, converted in-register to hi/lo A-frags.
// 3-term MFMA: Ah*Bh + Al*Bh + Ah*Bl  (error ~2^-16 rel).
// Outputs (same layouts as R3):
//   z=0 q: qh/ql [(a*8+h)*384+n]*32+c
//   z=1 k: kh/kl [((e*8+h)*4+(c>>3))*384+m]*8+(c&7)
//   z=2 v: vh    [(e*8+h)*32+c]*384+m   (via LDS transpose, hi only)
// ---------------------------------------------------------------------------
__global__ __launch_bounds__(128) void proj_mfma_kernel(
    const float* __restrict__ Xq, const float* __restrict__ Xk,
    const float* __restrict__ Xv,
    const float* __restrict__ Wq, const float* __restrict__ bq,
    const float* __restrict__ Wk, const float* __restrict__ bk,
    const float* __restrict__ Wv, const float* __restrict__ bv,
    ushort* __restrict__ qh, ushort* __restrict__ ql,
    ushort* __restrict__ kh, ushort* __restrict__ kl,
    ushort* __restrict__ vh)
{
    __shared__ ushort smem[2][16384];   // [hi/lo][ (kk*4+lg)*64*8 + col*8 + i ]

    const int z = blockIdx.z;
    const float* X    = (z == 0) ? Xq : (z == 1) ? Xk : Xv;
    const float* W    = (z == 0) ? Wq : (z == 1) ? Wk : Wv;
    const float* bias = (z == 0) ? bq : (z == 1) ? bk : bv;

    const int tid  = threadIdx.x;
    const int row0 = blockIdx.x * 64;
    const int col0 = blockIdx.y * 64;

    // ---- stage W hi/lo into LDS in B-frag-native layout ----
    #pragma unroll
    for (int i = 0; i < 32; ++i) {
        const int idx4 = tid + 128 * i;        // 0..4095 float4s
        const int col  = idx4 >> 6;            // 0..63
        const int k4   = (idx4 & 63) * 4;      // 0..252
        const float4 wv = *(const float4*)&W[(col0 + col) * 256 + k4];
        const int kk = k4 >> 5;
        const int lg = (k4 >> 3) & 3;
        const int i0 = k4 & 7;                 // 0 or 4
        const int base = ((kk * 4 + lg) * 64 + col) * 8 + i0;
        ushort hb[4], lb[4];
        const float w0[4] = {wv.x, wv.y, wv.z, wv.w};
        #pragma unroll
        for (int j = 0; j < 4; ++j) {
            hb[j] = f2bf(w0[j]);
            lb[j] = f2bf(w0[j] - bf2f(hb[j]));
        }
        *(uint2*)&smem[0][base] = *(const uint2*)&hb[0];
        *(uint2*)&smem[1][base] = *(const uint2*)&lb[0];
    }
    __syncthreads();

    const int wave = tid >> 6;
    const int lane = tid & 63;
    const int lg   = lane >> 4;
    const int ll   = lane & 15;

    f32x4 acc[2][4];
    #pragma unroll
    for (int r = 0; r < 2; ++r)
        #pragma unroll
        for (int c = 0; c < 4; ++c) acc[r][c] = (f32x4){0.f, 0.f, 0.f, 0.f};

    for (int kk = 0; kk < 8; ++kk) {
        s8x8 ah[2], al[2];
        #pragma unroll
        for (int rt = 0; rt < 2; ++rt) {
            const int row = row0 + wave * 32 + rt * 16 + ll;
            const float* xp = &X[(size_t)row * 256 + kk * 32 + lg * 8];
            const float4 x0 = *(const float4*)&xp[0];
            const float4 x1 = *(const float4*)&xp[4];
            const float xv[8] = {x0.x, x0.y, x0.z, x0.w, x1.x, x1.y, x1.z, x1.w};
            #pragma unroll
            for (int j = 0; j < 8; ++j) {
                const ushort hb = f2bf(xv[j]);
                ah[rt][j] = (short)hb;
                al[rt][j] = (short)f2bf(xv[j] - bf2f(hb));
            }
        }
        #pragma unroll
        for (int ct = 0; ct < 4; ++ct) {
            const int boff = ((kk * 4 + lg) * 64 + ct * 16 + ll) * 8;
            const s8x8 bh = *(const s8x8*)&smem[0][boff];
            const s8x8 bl = *(const s8x8*)&smem[1][boff];
            #pragma unroll
            for (int rt = 0; rt < 2; ++rt) {
                acc[rt][ct] = __builtin_amdgcn_mfma_f32_16x16x32_bf16(ah[rt], bh, acc[rt][ct], 0, 0, 0);
                acc[rt][ct] = __builtin_amdgcn_mfma_f32_16x16x32_bf16(al[rt], bh, acc[rt][ct], 0, 0, 0);
                acc[rt][ct] = __builtin_amdgcn_mfma_f32_16x16x32_bf16(ah[rt], bl, acc[rt][ct], 0, 0, 0);
            }
        }
    }

    float bct[4];
    #pragma unroll
    for (int ct = 0; ct < 4; ++ct) bct[ct] = bias[col0 + ct * 16 + ll];

    if (z != 2) {
        #pragma unroll
        for (int rt = 0; rt < 2; ++rt) {
            #pragma unroll
            for (int j = 0; j < 4; ++j) {
                const int row = row0 + wave * 32 + rt * 16 + lg * 4 + j;
                const int ae = row / 384;
                const int n = row - ae * 384;
                #pragma unroll
                for (int ct = 0; ct < 4; ++ct) {
                    const int d = col0 + ct * 16 + ll;
                    const int hd = d >> 5;
                    const int c = d & 31;
                    const float v = acc[rt][ct][j] + bct[ct];
                    const ushort hb = f2bf(v);
                    const ushort lb = f2bf(v - bf2f(hb));
                    if (z == 0) {
                        const size_t idx = ((size_t)((ae * 8 + hd) * 384 + n)) * 32 + c;
                        qh[idx] = hb; ql[idx] = lb;
                    } else {
                        const size_t idx =
                            ((size_t)(((ae * 8 + hd) * 4 + (c >> 3)) * 384 + n)) * 8 + (c & 7);
                        kh[idx] = hb; kl[idx] = lb;
                    }
                }
            }
        }
    } else {
        // V: fp32 tile -> LDS (reusing W storage) -> transposed bf16 stores
        __syncthreads();                       // all waves done reading W
        float* T = (float*)&smem[0][0];        // [64][65]
        #pragma unroll
        for (int rt = 0; rt < 2; ++rt)
            #pragma unroll
            for (int j = 0; j < 4; ++j) {
                const int rl = wave * 32 + rt * 16 + lg * 4 + j;
                #pragma unroll
                for (int ct = 0; ct < 4; ++ct)
                    T[rl * 65 + ct * 16 + ll] = acc[rt][ct][j] + bct[ct];
            }
        __syncthreads();
        const int col_l = tid >> 1;            // 0..63
        const int mh    = (tid & 1) * 32;      // m sub-chunk
        const int d = col0 + col_l;
        const int hd = d >> 5;
        const int c = d & 31;
        const int e = row0 / 384;
        const int m0 = row0 - e * 384;
        ushort hbuf[32] __attribute__((aligned(16)));
        #pragma unroll
        for (int k32 = 0; k32 < 32; ++k32)
            hbuf[k32] = f2bf(T[(mh + k32) * 65 + col_l]);
        const size_t base = (size_t)((e * 8 + hd) * 32 + c) * 384 + m0 + mh;
        #pragma unroll
        for (int u = 0; u < 4; ++u)
            *(uint4*)&vh[base + u * 8] = *(const uint4*)&hbuf[u * 8];
    }
}

// ---------------------------------------------------------------------------
// Kernel 2: MFMA flash attention per (a,e,h) x n-strip(96).
// grid (4, 128), block 192 (3 waves, 2 row-tiles of 16 each).
// m processed in two staged halves of 192. No online max (|s*sc| <= ~6).
// 3-term hi/lo QK^T, 2-term hi/lo PV. Writes normalized S + rawsum partial.
// ---------------------------------------------------------------------------
__global__ __launch_bounds__(192) void attn_mfma_kernel(
    const ushort* __restrict__ qhb, const ushort* __restrict__ qlb,
    const ushort* __restrict__ khb, const ushort* __restrict__ klb,
    const ushort* __restrict__ vhb,
    float* __restrict__ Sout, float* __restrict__ msum_part)
{
    __shared__ ushort Kh[4 * 192 * 8];
    __shared__ ushort Kl[4 * 192 * 8];
    __shared__ ushort Vh[32 * 200];
    __shared__ float  Pl[3][2][16][36];
    __shared__ float  red[192];

    const int strip = blockIdx.x;
    const int aeh   = blockIdx.y;          // a*32 + e*8 + h
    const int hh    = aeh & 7;
    const int ee    = (aeh >> 3) & 3;
    const int aa    = aeh >> 5;
    const int e8h   = ee * 8 + hh;
    const int a8h   = aa * 8 + hh;
    const int tid   = threadIdx.x;
    const int wave  = tid >> 6;
    const int lane  = tid & 63;
    const int lg    = lane >> 4;
    const int ll    = lane & 15;

    // Q A-fragments (hi/lo) for this wave's two row-tiles, straight from global
    s8x8 qfh[2], qfl[2];
    #pragma unroll
    for (int r = 0; r < 2; ++r) {
        const int n0 = strip * 96 + (2 * wave + r) * 16;
        const size_t off = (size_t)(a8h * 384 + n0 + ll) * 32 + lg * 8;
        qfh[r] = *(const s8x8*)&qhb[off];
        qfl[r] = *(const s8x8*)&qlb[off];
    }

    f32x4 oacc[2][2];
    #pragma unroll
    for (int r = 0; r < 2; ++r)
        #pragma unroll
        for (int ct = 0; ct < 2; ++ct)
            oacc[r][ct] = (f32x4){0.f, 0.f, 0.f, 0.f};
    float lsum[2][4];
    #pragma unroll
    for (int r = 0; r < 2; ++r)
        #pragma unroll
        for (int j = 0; j < 4; ++j) lsum[r][j] = 0.f;
    float rs = 0.f;
    const float sc = 0.17677669529663687f; // 1/sqrt(32)

    for (int half = 0; half < 2; ++half) {
        #pragma unroll
        for (int i = 0; i < 4; ++i) {
            const size_t src = ((size_t)(e8h * 4 + i) * 384 + half * 192 + tid) * 8;
            *(uint4*)&Kh[(i * 192 + tid) * 8] = *(const uint4*)&khb[src];
            *(uint4*)&Kl[(i * 192 + tid) * 8] = *(const uint4*)&klb[src];
        }
        #pragma unroll
        for (int i = 0; i < 4; ++i) {
            const int u = tid + 192 * i;
            const int c = u / 24;
            const int m8 = (u - c * 24) * 8;
            *(uint4*)&Vh[c * 200 + m8] =
                *(const uint4*)&vhb[(size_t)(e8h * 32 + c) * 384 + half * 192 + m8];
        }
        __syncthreads();

        for (int mt2 = 0; mt2 < 6; ++mt2) {
            #pragma unroll
            for (int sub = 0; sub < 2; ++sub) {
                const int mt = mt2 * 2 + sub;
                const s8x8 kfh = *(const s8x8*)&Kh[(lg * 192 + mt * 16 + ll) * 8];
                const s8x8 kfl = *(const s8x8*)&Kl[(lg * 192 + mt * 16 + ll) * 8];
                #pragma unroll
                for (int r = 0; r < 2; ++r) {
                    f32x4 s = {0.f, 0.f, 0.f, 0.f};
                    __builtin_amdgcn_s_setprio(1);
                    s = __builtin_amdgcn_mfma_f32_16x16x32_bf16(qfh[r], kfh, s, 0, 0, 0);
                    s = __builtin_amdgcn_mfma_f32_16x16x32_bf16(qfl[r], kfh, s, 0, 0, 0);
                    s = __builtin_amdgcn_mfma_f32_16x16x32_bf16(qfh[r], kfl, s, 0, 0, 0);
                    __builtin_amdgcn_s_setprio(0);
                    rs += s[0] + s[1] + s[2] + s[3];
                    #pragma unroll
                    for (int j = 0; j < 4; ++j) {
                        const float p = __expf(s[j] * sc);
                        lsum[r][j] += p;
                        Pl[wave][r][lg * 4 + j][sub * 16 + ll] = p;
                    }
                }
            }
            // PV over the 32 freshly produced columns
            const int mloc = mt2 * 32;
            const s8x8 vf0 = *(const s8x8*)&Vh[(0  + ll) * 200 + mloc + lg * 8];
            const s8x8 vf1 = *(const s8x8*)&Vh[(16 + ll) * 200 + mloc + lg * 8];
            #pragma unroll
            for (int r = 0; r < 2; ++r) {
                const float* prow = &Pl[wave][r][ll][lg * 8];
                s8x8 pah, pal;
                #pragma unroll
                for (int e2 = 0; e2 < 8; ++e2) {
                    const float pv = prow[e2];
                    const ushort hb = f2bf(pv);
                    pah[e2] = (short)hb;
                    pal[e2] = (short)f2bf(pv - bf2f(hb));
                }
                __builtin_amdgcn_s_setprio(1);
                oacc[r][0] = __builtin_amdgcn_mfma_f32_16x16x32_bf16(pah, vf0, oacc[r][0], 0, 0, 0);
                oacc[r][0] = __builtin_amdgcn_mfma_f32_16x16x32_bf16(pal, vf0, oacc[r][0], 0, 0, 0);
                oacc[r][1] = __builtin_amdgcn_mfma_f32_16x16x32_bf16(pah, vf1, oacc[r][1], 0, 0, 0);
                oacc[r][1] = __builtin_amdgcn_mfma_f32_16x16x32_bf16(pal, vf1, oacc[r][1], 0, 0, 0);
                __builtin_amdgcn_s_setprio(0);
            }
        }
        __syncthreads();
    }

    // finalize: per-row L (reduce across the 16 col-lanes), normalize, write S
    #pragma unroll
    for (int r = 0; r < 2; ++r) {
        #pragma unroll
        for (int j = 0; j < 4; ++j) {
            float L = lsum[r][j];
            L += __shfl_xor(L, 1);
            L += __shfl_xor(L, 2);
            L += __shfl_xor(L, 4);
            L += __shfl_xor(L, 8);
            const float invL = 1.f / L;
            const int row = strip * 96 + (2 * wave + r) * 16 + lg * 4 + j;
            const size_t base = (size_t)(aeh * 384 + row) * 32;
            Sout[base + 0  + ll] = oacc[r][0][j] * invL;
            Sout[base + 16 + ll] = oacc[r][1][j] * invL;
        }
    }

    // rawsum partial (scale once by sc), deterministic block tree
    red[tid] = rs * sc;
    __syncthreads();
    for (int off = 96; off >= 3; off >>= 1) {
        if (tid < off) red[tid] += red[tid + off];
        __syncthreads();
    }
    if (tid == 0) msum_part[aeh * 4 + strip] = red[0] + red[1] + red[2];
}

// ---------------------------------------------------------------------------
// Kernel 3: 512 partials -> 16 cell sums -> pooled[12] -> weights[16]
// ---------------------------------------------------------------------------
__global__ __launch_bounds__(256) void stats_kernel(
    const float* __restrict__ msum_part, float* __restrict__ wout)
{
    __shared__ float sh[128];
    __shared__ float cell[16];
    const int tid = threadIdx.x;
    if (tid < 128) {
        float s = 0.f;
        #pragma unroll
        for (int j = 0; j < 4; ++j) s += msum_part[tid * 4 + j];
        sh[tid] = s;
    }
    __syncthreads();
    if (tid < 16) {
        const int base = (tid >> 2) * 32 + (tid & 3) * 8; // a*32 + e*8
        float s = 0.f;
        #pragma unroll
        for (int hh = 0; hh < 8; ++hh) s += sh[base + hh];
        cell[tid] = s;
    }
    __syncthreads();
    if (tid == 0) {
        const int TR[12][4] = {
            {0,1,2,3},{0,2,3,1},{0,3,1,2},{1,2,0,3},{1,0,3,2},{1,3,2,0},
            {2,3,0,1},{2,0,1,3},{2,1,3,0},{3,1,0,2},{3,0,2,1},{3,2,1,0}};
        const float denom = 4.0f * 8.0f * 384.0f * 384.0f;
        float pos[12];
        float psum = 0.f;
        for (int r = 0; r < 12; ++r) {
            float s = 0.f;
            for (int aa = 0; aa < 4; ++aa) s += cell[aa * 4 + TR[r][aa]];
            const float pooled = s / denom;
            pos[r] = pooled * pooled;
            psum += pos[r];
        }
        float w[16];
        for (int i = 0; i < 16; ++i) w[i] = 0.f;
        const float ip = 1.f / psum;
        for (int r = 0; r < 12; ++r)
            for (int aa = 0; aa < 4; ++aa) w[aa * 4 + TR[r][aa]] += pos[r] * ip;
        for (int i = 0; i < 16; ++i) wout[i] = w[i];
    }
}

// ---------------------------------------------------------------------------
// Kernel 4: out[a,n,h*32+c] = sum_e w[a,e] * S[(a,e),h,n,c]
// ---------------------------------------------------------------------------
__global__ __launch_bounds__(256) void combine_kernel(
    const float* __restrict__ S, const float* __restrict__ w,
    float* __restrict__ out)
{
    const int idx = blockIdx.x * 256 + threadIdx.x;
    const int a = idx / 98304;
    const int rem = idx - a * 98304;
    const int n = rem >> 8;
    const int d = rem & 255;
    const int h = d >> 5;
    const int c = d & 31;
    float r = 0.f;
    #pragma unroll
    for (int e = 0; e < 4; ++e)
        r += w[a * 4 + e] * S[(size_t)(((a * 4 + e) * 8 + h) * 384 + n) * 32 + c];
    out[idx] = r;
}

// ---------------------------------------------------------------------------
extern "C" void kernel_launch(void* const* d_in, const int* in_sizes, int n_in,
                              void* d_out, int out_size, void* d_ws, size_t ws_size,
                              hipStream_t stream)
{
    const float* in_q = (const float*)d_in[0];
    const float* in_k = (const float*)d_in[1];
    const float* in_v = (const float*)d_in[2];
    const float* Wq   = (const float*)d_in[3];
    const float* bq   = (const float*)d_in[4];
    const float* Wk   = (const float*)d_in[5];
    const float* bk   = (const float*)d_in[6];
    const float* Wv   = (const float*)d_in[7];
    const float* bv   = (const float*)d_in[8];

    const size_t NE = 393216; // elements per projected tensor
    ushort* qh = (ushort*)d_ws;
    ushort* ql = qh + NE;
    ushort* kh = ql + NE;
    ushort* kl = kh + NE;
    ushort* vh = kl + NE;
    float*  Sb = (float*)((char*)d_ws + 5 * NE * sizeof(ushort));
    float*  ms = Sb + 1572864;   // 512 partials
    float*  wb = ms + 512;       // 16 weights
    float*  outp = (float*)d_out;

    dim3 pgrid(24, 4, 3);
    proj_mfma_kernel<<<pgrid, 128, 0, stream>>>(in_q, in_k, in_v, Wq, bq, Wk, bk,
                                                Wv, bv, qh, ql, kh, kl, vh);
    dim3 agrid(4, 128);
    attn_mfma_kernel<<<agrid, 192, 0, stream>>>(qh, ql, kh, kl, vh, Sb, ms);
    stats_kernel<<<1, 256, 0, stream>>>(ms, wb);
    combine_kernel<<<1536, 256, 0, stream>>>(Sb, wb, outp);
}